// Round 4
// baseline (752.690 us; speedup 1.0000x reference)
//
#include <hip/hip_runtime.h>

// FlashAttention B=2,H=16,S=2048,D=64. fp32 in/out, int32 mask.
// Mask stream (537 MB) is the HBM roofline. Pack kernel -> bf16 MFMA fragments
// in d_ws. Main kernel: 512 blocks (exactly 2/CU, one balanced round), each
// block does TWO 64-query strips sharing K/V LDS reads; lag-1 PV pipeline;
// async global_load_lds double-buffered K/V; fixed-max softmax.

typedef __attribute__((ext_vector_type(8))) short bf16x8;
typedef __attribute__((ext_vector_type(4))) short s16x4;
typedef __attribute__((ext_vector_type(4))) float f32x4;

#define S_LEN 2048
#define NT 32
#define PP 72
#define QSCALE 0.1803368801f   // (1/8)*log2(e): exp(s/8) == exp2(s*QSCALE)

__device__ __forceinline__ short f2bf(float f) {
    union { float f; unsigned u; } v; v.f = f;
    unsigned r = v.u + 0x7fffu + ((v.u >> 16) & 1u);
    return (short)(r >> 16);
}

__device__ __forceinline__ float fexp2(float x) {
#if __has_builtin(__builtin_amdgcn_exp2f)
    return __builtin_amdgcn_exp2f(x);
#else
    return exp2f(x);
#endif
}

#if __has_builtin(__builtin_amdgcn_cvt_pk_bf16_f32)
typedef __attribute__((ext_vector_type(2))) __bf16 bf16x2_t;
__device__ __forceinline__ unsigned pk2(float a, float b) {
    bf16x2_t v = __builtin_amdgcn_cvt_pk_bf16_f32(a, b);
    union { bf16x2_t v; unsigned u; } u; u.v = v; return u.u;
}
#else
__device__ __forceinline__ unsigned pk2(float a, float b) {
    return (unsigned)(unsigned short)f2bf(a) | ((unsigned)(unsigned short)f2bf(b) << 16);
}
#endif

__device__ __forceinline__ bf16x8 cvt8(float4 a, float4 b, float s) {
    bf16x8 f;
    f[0]=f2bf(a.x*s); f[1]=f2bf(a.y*s); f[2]=f2bf(a.z*s); f[3]=f2bf(a.w*s);
    f[4]=f2bf(b.x*s); f[5]=f2bf(b.y*s); f[6]=f2bf(b.z*s); f[7]=f2bf(b.w*s);
    return f;
}

// ---- merged pack: z=0 Q (A-frag, pre-scaled), z=1 K (B-frag, key perm 4c+nb),
// ----              z=2 V (B-frag for PV, identity key order)
__global__ __launch_bounds__(256)
void pack_all(const float* __restrict__ Q, const float* __restrict__ K,
              const float* __restrict__ V, short* __restrict__ Qw,
              short* __restrict__ Kw, short* __restrict__ Vw) {
    __shared__ float vt[64][65];
    const int bh = blockIdx.x, t = blockIdx.y, which = blockIdx.z;
    if (which == 0) {
        for (int ci = threadIdx.x; ci < 512; ci += 256) {
            int ww = ci >> 7, ks = (ci >> 6) & 1, lane = ci & 63;
            int quad = lane >> 4, c = lane & 15;
            int row = t * 64 + ww * 16 + c;
            int d0 = ks * 32 + quad * 8;
            const float* src = Q + ((size_t)(bh * S_LEN + row)) * 64 + d0;
            float4 a = *(const float4*)src;
            float4 b = *(const float4*)(src + 4);
            *(bf16x8*)(Qw + ((size_t)(bh * 32 + t) * 512 + ci) * 8) = cvt8(a, b, QSCALE);
        }
    } else if (which == 1) {
        for (int ci = threadIdx.x; ci < 512; ci += 256) {
            int fb = ci >> 6, lane = ci & 63;
            int nb = fb >> 1, ks = fb & 1;
            int quad = lane >> 4, c = lane & 15;
            int key = t * 64 + c * 4 + nb;              // in-tile key permutation
            int d0 = ks * 32 + quad * 8;
            const float* src = K + ((size_t)(bh * S_LEN + key)) * 64 + d0;
            float4 a = *(const float4*)src;
            float4 b = *(const float4*)(src + 4);
            *(bf16x8*)(Kw + ((size_t)(bh * 32 + t) * 512 + ci) * 8) = cvt8(a, b, 1.0f);
        }
    } else {
        {
            int key = threadIdx.x >> 2, d0 = (threadIdx.x & 3) * 16;
            const float* src = V + ((size_t)(bh * S_LEN + t * 64 + key)) * 64 + d0;
            float4 a = *(const float4*)src;
            float4 b = *(const float4*)(src + 4);
            float4 cc = *(const float4*)(src + 8);
            float4 d = *(const float4*)(src + 12);
            float* dst = &vt[key][d0];
            dst[0]=a.x; dst[1]=a.y; dst[2]=a.z; dst[3]=a.w;
            dst[4]=b.x; dst[5]=b.y; dst[6]=b.z; dst[7]=b.w;
            dst[8]=cc.x; dst[9]=cc.y; dst[10]=cc.z; dst[11]=cc.w;
            dst[12]=d.x; dst[13]=d.y; dst[14]=d.z; dst[15]=d.w;
        }
        __syncthreads();
        for (int ci = threadIdx.x; ci < 512; ci += 256) {
            int fb = ci >> 6, lane = ci & 63;
            int db = fb >> 1, ks = fb & 1;
            int quad = lane >> 4, c = lane & 15;
            bf16x8 f;
#pragma unroll
            for (int j = 0; j < 8; ++j) {
                int pos = ks * 32 + quad * 8 + j;       // identity key order
                f[j] = f2bf(vt[pos][db * 16 + c]);
            }
            *(bf16x8*)(Vw + ((size_t)(bh * 32 + t) * 512 + ci) * 8) = f;
        }
    }
}

typedef __attribute__((address_space(3))) unsigned lds_u32;
typedef const __attribute__((address_space(1))) unsigned glob_u32;

#define MFMA(a, b, acc) __builtin_amdgcn_mfma_f32_16x16x32_bf16(a, b, acc, 0, 0, 0)

__global__ __launch_bounds__(256, 2)
void fa_main(const short* __restrict__ Qw, const short* __restrict__ Kw,
             const short* __restrict__ Vw, const int* __restrict__ M,
             float* __restrict__ O) {
    __shared__ __align__(16) short Kb[2 * 8 * 512];    // 16 KB K double-buffer
    __shared__ __align__(16) short Vb[2 * 8 * 512];    // 16 KB V double-buffer (lagged)
    __shared__ __align__(16) short Pwv[8 * 16 * PP];   // 18 KB P staging (2 strips x 4 waves)

    const int tid  = threadIdx.x;
    const int lane = tid & 63;
    const int w    = tid >> 6;
    const int quad = lane >> 4;
    const int c    = lane & 15;

    const int bid = blockIdx.x;          // 512 blocks = exactly 2/CU
    const int x = bid & 7, y = bid >> 3; // y: 0..63
    const int bh = x * 4 + (y >> 4);     // 4 heads per XCD
    const int p  = y & 15;               // 128-query pair index

    // Q fragments for both strips (tiles 2p, 2p+1)
    bf16x8 qf[2][2];
#pragma unroll
    for (int s = 0; s < 2; ++s) {
        const short* qb = Qw + ((size_t)(bh * 32 + 2 * p + s) * 512 + w * 128 + lane) * 8;
        qf[s][0] = *(const bf16x8*)qb;
        qf[s][1] = *(const bf16x8*)(qb + 512);
    }

    // DMA plan: waves 0,1 stage K tile t+1; waves 2,3 stage V tile t (lagged)
    const bool isK = (w < 2);
    const short* gsrc = (isK ? Kw : Vw) + (size_t)bh * 32 * 4096 + (w & 1) * 2048 + (size_t)lane * 8;
    short* ldst0 = (isK ? Kb : Vb) + (w & 1) * 2048;

    const int* mrow[2];
    mrow[0] = M + ((size_t)(bh * S_LEN + p * 128 + w * 16 + quad * 4)) * S_LEN + 4 * c;
    mrow[1] = mrow[0] + (size_t)64 * S_LEN;

    f32x4 acco[2][4];
    float lacc[2][4];
#pragma unroll
    for (int s = 0; s < 2; ++s)
#pragma unroll
        for (int r = 0; r < 4; ++r) {
            lacc[s][r] = 0.f;
            acco[s][r][0]=0.f; acco[s][r][1]=0.f; acco[s][r][2]=0.f; acco[s][r][3]=0.f;
        }

    // prologue: K(0) -> Kb[0]; mask tile 0 for both strips
    if (isK) {
#pragma unroll
        for (int i = 0; i < 4; ++i)
            __builtin_amdgcn_global_load_lds((glob_u32*)(gsrc + i * 512),
                                             (lds_u32*)(ldst0 + i * 512), 16, 0, 0);
    }
    int4 mcur[2][4];
#pragma unroll
    for (int s = 0; s < 2; ++s)
#pragma unroll
        for (int r = 0; r < 4; ++r)
            mcur[s][r] = *(const int4*)(mrow[s] + (size_t)r * S_LEN);
    __syncthreads();

    short* pw[2];
    pw[0] = &Pwv[(0 + w) * 16 * PP];
    pw[1] = &Pwv[(4 + w) * 16 * PP];
    const short* pr0 = pw[0] + c * PP;
    const short* pr1 = pw[1] + c * PP;

    for (int t = 0; t < NT; ++t) {
        const int tn = (t + 1) & (NT - 1);
        const int dtile = isK ? tn : t;              // K fetches t+1, V fetches t
        const int dbuf = (dtile & 1) * 4096;
#pragma unroll
        for (int i = 0; i < 4; ++i)
            __builtin_amdgcn_global_load_lds((glob_u32*)(gsrc + (size_t)dtile * 4096 + i * 512),
                                             (lds_u32*)(ldst0 + dbuf + i * 512), 16, 0, 0);
        int4 mnxt[2][4];
#pragma unroll
        for (int s = 0; s < 2; ++s)
#pragma unroll
            for (int r = 0; r < 4; ++r)
                mnxt[s][r] = *(const int4*)(mrow[s] + (size_t)r * S_LEN + tn * 64);

        // ---- S(t) = Qs K^T, both strips share each K fragment read ----
        const int kc = (t & 1) * 4096;
        f32x4 accs[2][4];
#pragma unroll
        for (int s = 0; s < 2; ++s)
#pragma unroll
            for (int nb = 0; nb < 4; ++nb) { accs[s][nb][0]=0.f; accs[s][nb][1]=0.f; accs[s][nb][2]=0.f; accs[s][nb][3]=0.f; }
#pragma unroll
        for (int nb = 0; nb < 4; ++nb) {
            bf16x8 b0 = *(const bf16x8*)&Kb[kc + (nb * 2 + 0) * 512 + lane * 8];
            bf16x8 b1 = *(const bf16x8*)&Kb[kc + (nb * 2 + 1) * 512 + lane * 8];
            accs[0][nb] = MFMA(qf[0][0], b0, accs[0][nb]);
            accs[0][nb] = MFMA(qf[0][1], b1, accs[0][nb]);
            accs[1][nb] = MFMA(qf[1][0], b0, accs[1][nb]);
            accs[1][nb] = MFMA(qf[1][1], b1, accs[1][nb]);
        }

        // ---- PV(t-1): V fragments shared across strips; P read before rewrite ----
        if (t > 0) {
            const int vc = ((t - 1) & 1) * 4096;
            bf16x8 pf00 = *(const bf16x8*)(pr0 + quad * 8);
            bf16x8 pf01 = *(const bf16x8*)(pr0 + 32 + quad * 8);
            bf16x8 pf10 = *(const bf16x8*)(pr1 + quad * 8);
            bf16x8 pf11 = *(const bf16x8*)(pr1 + 32 + quad * 8);
#pragma unroll
            for (int db = 0; db < 4; ++db) {
                bf16x8 v0 = *(const bf16x8*)&Vb[vc + (db * 2 + 0) * 512 + lane * 8];
                bf16x8 v1 = *(const bf16x8*)&Vb[vc + (db * 2 + 1) * 512 + lane * 8];
                acco[0][db] = MFMA(pf00, v0, acco[0][db]);
                acco[0][db] = MFMA(pf01, v1, acco[0][db]);
                acco[1][db] = MFMA(pf10, v0, acco[1][db]);
                acco[1][db] = MFMA(pf11, v1, acco[1][db]);
            }
        }

        // ---- p = mask ? exp2(s') : 0 ; row-sum partials; b64 P write ----
#pragma unroll
        for (int s = 0; s < 2; ++s) {
            short* pws = pw[s];
#pragma unroll
            for (int r = 0; r < 4; ++r) {
                const int4 mm = mcur[s][r];
                float e0 = fexp2(accs[s][0][r]); e0 = (mm.x != 0) ? e0 : 0.f;
                float e1 = fexp2(accs[s][1][r]); e1 = (mm.y != 0) ? e1 : 0.f;
                float e2 = fexp2(accs[s][2][r]); e2 = (mm.z != 0) ? e2 : 0.f;
                float e3 = fexp2(accs[s][3][r]); e3 = (mm.w != 0) ? e3 : 0.f;
                lacc[s][r] += (e0 + e1) + (e2 + e3);
                union { unsigned u[2]; s16x4 v; } pk;
                pk.u[0] = pk2(e0, e1);
                pk.u[1] = pk2(e2, e3);
                *(s16x4*)&pws[(quad * 4 + r) * PP + 4 * c] = pk.v;  // key pos 4c+nb
            }
        }
#pragma unroll
        for (int s = 0; s < 2; ++s)
#pragma unroll
            for (int r = 0; r < 4; ++r) mcur[s][r] = mnxt[s][r];
        __syncthreads();
    }

    // ---- drain: PV(NT-1) from Vb[1] ----
    {
        const int vc = ((NT - 1) & 1) * 4096;
        bf16x8 pf00 = *(const bf16x8*)(pr0 + quad * 8);
        bf16x8 pf01 = *(const bf16x8*)(pr0 + 32 + quad * 8);
        bf16x8 pf10 = *(const bf16x8*)(pr1 + quad * 8);
        bf16x8 pf11 = *(const bf16x8*)(pr1 + 32 + quad * 8);
#pragma unroll
        for (int db = 0; db < 4; ++db) {
            bf16x8 v0 = *(const bf16x8*)&Vb[vc + (db * 2 + 0) * 512 + lane * 8];
            bf16x8 v1 = *(const bf16x8*)&Vb[vc + (db * 2 + 1) * 512 + lane * 8];
            acco[0][db] = MFMA(pf00, v0, acco[0][db]);
            acco[0][db] = MFMA(pf01, v1, acco[0][db]);
            acco[1][db] = MFMA(pf10, v0, acco[1][db]);
            acco[1][db] = MFMA(pf11, v1, acco[1][db]);
        }
    }

    // ---- epilogue ----
#pragma unroll
    for (int s = 0; s < 2; ++s) {
        float* orow = O + ((size_t)(bh * S_LEN + p * 128 + s * 64 + w * 16 + quad * 4)) * 64 + c;
#pragma unroll
        for (int r = 0; r < 4; ++r) {
            float l = lacc[s][r];
            l += __shfl_xor(l, 1);
            l += __shfl_xor(l, 2);
            l += __shfl_xor(l, 4);
            l += __shfl_xor(l, 8);
            float inv = 1.0f / l;
#pragma unroll
            for (int db = 0; db < 4; ++db)
                orow[(size_t)r * 64 + db * 16] = acco[s][db][r] * inv;
        }
    }
}

extern "C" void kernel_launch(void* const* d_in, const int* in_sizes, int n_in,
                              void* d_out, int out_size, void* d_ws, size_t ws_size,
                              hipStream_t stream) {
    const float* Q = (const float*)d_in[0];
    const float* K = (const float*)d_in[1];
    const float* V = (const float*)d_in[2];
    const int*   M = (const int*)d_in[3];
    float* O = (float*)d_out;

    short* Qw = (short*)d_ws;                       // 8 MB
    short* Kw = Qw + (size_t)32 * 32 * 4096;        // 8 MB
    short* Vw = Kw + (size_t)32 * 32 * 4096;        // 8 MB

    hipLaunchKernelGGL(pack_all, dim3(32, 32, 3), dim3(256), 0, stream, Q, K, V, Qw, Kw, Vw);
    hipLaunchKernelGGL(fa_main, dim3(512), dim3(256), 0, stream, Qw, Kw, Vw, M, O);
}

// Round 5
// 728.688 us; speedup vs baseline: 1.0329x; 1.0329x over previous
//
#include <hip/hip_runtime.h>

// FlashAttention B=2,H=16,S=2048,D=64. fp32 in/out, int32 mask.
// dur_us is dominated by harness resets (~600us: 2GiB ws poison + 1.2GB input
// restores); controllable part is mask-stream-bound (537MB). This round: drop
// Q pack (build Q frags from raw Q in fa_main prologue), coalesce K pack via
// LDS staging, non-temporal mask loads to protect L2-resident K/V tiles.

typedef __attribute__((ext_vector_type(8))) short bf16x8;
typedef __attribute__((ext_vector_type(4))) short s16x4;
typedef __attribute__((ext_vector_type(4))) float f32x4;
typedef __attribute__((ext_vector_type(4))) int   i32x4;

#define S_LEN 2048
#define NT 32
#define PP 72
#define QSCALE 0.1803368801f   // (1/8)*log2(e): exp(s/8) == exp2(s*QSCALE)

__device__ __forceinline__ short f2bf(float f) {
    union { float f; unsigned u; } v; v.f = f;
    unsigned r = v.u + 0x7fffu + ((v.u >> 16) & 1u);
    return (short)(r >> 16);
}

__device__ __forceinline__ float fexp2(float x) {
#if __has_builtin(__builtin_amdgcn_exp2f)
    return __builtin_amdgcn_exp2f(x);
#else
    return exp2f(x);
#endif
}

#if __has_builtin(__builtin_amdgcn_cvt_pk_bf16_f32)
typedef __attribute__((ext_vector_type(2))) __bf16 bf16x2_t;
__device__ __forceinline__ unsigned pk2(float a, float b) {
    bf16x2_t v = __builtin_amdgcn_cvt_pk_bf16_f32(a, b);
    union { bf16x2_t v; unsigned u; } u; u.v = v; return u.u;
}
#else
__device__ __forceinline__ unsigned pk2(float a, float b) {
    return (unsigned)(unsigned short)f2bf(a) | ((unsigned)(unsigned short)f2bf(b) << 16);
}
#endif

__device__ __forceinline__ i32x4 ntload4(const int* p) {
#if __has_builtin(__builtin_nontemporal_load)
    return __builtin_nontemporal_load((const i32x4*)p);
#else
    return *(const i32x4*)p;
#endif
}

__device__ __forceinline__ bf16x8 cvt8(float4 a, float4 b, float s) {
    bf16x8 f;
    f[0]=f2bf(a.x*s); f[1]=f2bf(a.y*s); f[2]=f2bf(a.z*s); f[3]=f2bf(a.w*s);
    f[4]=f2bf(b.x*s); f[5]=f2bf(b.y*s); f[6]=f2bf(b.z*s); f[7]=f2bf(b.w*s);
    return f;
}

// ---- pack K (z=0: B-frag, key perm 4c+nb) and V (z=1: B-frag for PV, identity),
// ---- both staged through LDS so global reads are fully coalesced.
__global__ __launch_bounds__(256)
void pack_kv(const float* __restrict__ K, const float* __restrict__ V,
             short* __restrict__ Kw, short* __restrict__ Vw) {
    __shared__ float vt[64][65];
    const int bh = blockIdx.x, t = blockIdx.y, which = blockIdx.z;
    const float* src_mat = (which == 0) ? K : V;
    {
        int row = threadIdx.x >> 2, d0 = (threadIdx.x & 3) * 16;
        const float* src = src_mat + ((size_t)(bh * S_LEN + t * 64 + row)) * 64 + d0;
        float4 a = *(const float4*)src;
        float4 b = *(const float4*)(src + 4);
        float4 cc = *(const float4*)(src + 8);
        float4 d = *(const float4*)(src + 12);
        float* dst = &vt[row][d0];
        dst[0]=a.x; dst[1]=a.y; dst[2]=a.z; dst[3]=a.w;
        dst[4]=b.x; dst[5]=b.y; dst[6]=b.z; dst[7]=b.w;
        dst[8]=cc.x; dst[9]=cc.y; dst[10]=cc.z; dst[11]=cc.w;
        dst[12]=d.x; dst[13]=d.y; dst[14]=d.z; dst[15]=d.w;
    }
    __syncthreads();
    if (which == 0) {
        for (int ci = threadIdx.x; ci < 512; ci += 256) {
            int fb = ci >> 6, lane = ci & 63;
            int nb = fb >> 1, ks = fb & 1;
            int quad = lane >> 4, c = lane & 15;
            bf16x8 f;
#pragma unroll
            for (int j = 0; j < 8; ++j)
                f[j] = f2bf(vt[c * 4 + nb][ks * 32 + quad * 8 + j]);  // key perm 4c+nb
            *(bf16x8*)(Kw + ((size_t)(bh * 32 + t) * 512 + ci) * 8) = f;
        }
    } else {
        for (int ci = threadIdx.x; ci < 512; ci += 256) {
            int fb = ci >> 6, lane = ci & 63;
            int db = fb >> 1, ks = fb & 1;
            int quad = lane >> 4, c = lane & 15;
            bf16x8 f;
#pragma unroll
            for (int j = 0; j < 8; ++j)
                f[j] = f2bf(vt[ks * 32 + quad * 8 + j][db * 16 + c]); // identity key order
            *(bf16x8*)(Vw + ((size_t)(bh * 32 + t) * 512 + ci) * 8) = f;
        }
    }
}

typedef __attribute__((address_space(3))) unsigned lds_u32;
typedef const __attribute__((address_space(1))) unsigned glob_u32;

#define MFMA(a, b, acc) __builtin_amdgcn_mfma_f32_16x16x32_bf16(a, b, acc, 0, 0, 0)

__global__ __launch_bounds__(256, 2)
void fa_main(const float* __restrict__ Q, const short* __restrict__ Kw,
             const short* __restrict__ Vw, const int* __restrict__ M,
             float* __restrict__ O) {
    __shared__ __align__(16) short Kb[2 * 8 * 512];    // 16 KB K double-buffer
    __shared__ __align__(16) short Vb[2 * 8 * 512];    // 16 KB V double-buffer (lagged)
    __shared__ __align__(16) short Pwv[8 * 16 * PP];   // 18 KB P staging (2 strips x 4 waves)

    const int tid  = threadIdx.x;
    const int lane = tid & 63;
    const int w    = tid >> 6;
    const int quad = lane >> 4;
    const int c    = lane & 15;

    const int bid = blockIdx.x;          // 512 blocks = exactly 2/CU
    const int x = bid & 7, y = bid >> 3; // y: 0..63
    const int bh = x * 4 + (y >> 4);     // 4 heads per XCD
    const int p  = y & 15;               // 128-query pair index

    // DMA plan: waves 0,1 stage K tile t+1; waves 2,3 stage V tile t (lagged)
    const bool isK = (w < 2);
    const short* gsrc = (isK ? Kw : Vw) + (size_t)bh * 32 * 4096 + (w & 1) * 2048 + (size_t)lane * 8;
    short* ldst0 = (isK ? Kb : Vb) + (w & 1) * 2048;

    // prologue: start K(0) DMA first so Q conversion hides under it
    if (isK) {
#pragma unroll
        for (int i = 0; i < 4; ++i)
            __builtin_amdgcn_global_load_lds((glob_u32*)(gsrc + i * 512),
                                             (lds_u32*)(ldst0 + i * 512), 16, 0, 0);
    }

    // Q fragments from raw Q (one-time, pre-scaled by QSCALE)
    bf16x8 qf[2][2];
#pragma unroll
    for (int s = 0; s < 2; ++s) {
        const float* qp = Q + ((size_t)(bh * S_LEN + p * 128 + s * 64 + w * 16 + c)) * 64 + quad * 8;
#pragma unroll
        for (int ks = 0; ks < 2; ++ks) {
            float4 a = *(const float4*)(qp + ks * 32);
            float4 b = *(const float4*)(qp + ks * 32 + 4);
            qf[s][ks] = cvt8(a, b, QSCALE);
        }
    }

    const int* mrow[2];
    mrow[0] = M + ((size_t)(bh * S_LEN + p * 128 + w * 16 + quad * 4)) * S_LEN + 4 * c;
    mrow[1] = mrow[0] + (size_t)64 * S_LEN;

    f32x4 acco[2][4];
    float lacc[2][4];
#pragma unroll
    for (int s = 0; s < 2; ++s)
#pragma unroll
        for (int r = 0; r < 4; ++r) {
            lacc[s][r] = 0.f;
            acco[s][r][0]=0.f; acco[s][r][1]=0.f; acco[s][r][2]=0.f; acco[s][r][3]=0.f;
        }

    i32x4 mcur[2][4];
#pragma unroll
    for (int s = 0; s < 2; ++s)
#pragma unroll
        for (int r = 0; r < 4; ++r)
            mcur[s][r] = ntload4(mrow[s] + (size_t)r * S_LEN);
    __syncthreads();

    short* pw[2];
    pw[0] = &Pwv[(0 + w) * 16 * PP];
    pw[1] = &Pwv[(4 + w) * 16 * PP];
    const short* pr0 = pw[0] + c * PP;
    const short* pr1 = pw[1] + c * PP;

    for (int t = 0; t < NT; ++t) {
        const int tn = (t + 1) & (NT - 1);
        const int dtile = isK ? tn : t;              // K fetches t+1, V fetches t
        const int dbuf = (dtile & 1) * 4096;
#pragma unroll
        for (int i = 0; i < 4; ++i)
            __builtin_amdgcn_global_load_lds((glob_u32*)(gsrc + (size_t)dtile * 4096 + i * 512),
                                             (lds_u32*)(ldst0 + dbuf + i * 512), 16, 0, 0);
        i32x4 mnxt[2][4];
#pragma unroll
        for (int s = 0; s < 2; ++s)
#pragma unroll
            for (int r = 0; r < 4; ++r)
                mnxt[s][r] = ntload4(mrow[s] + (size_t)r * S_LEN + tn * 64);

        // ---- S(t) = Qs K^T, both strips share each K fragment read ----
        const int kc = (t & 1) * 4096;
        f32x4 accs[2][4];
#pragma unroll
        for (int s = 0; s < 2; ++s)
#pragma unroll
            for (int nb = 0; nb < 4; ++nb) { accs[s][nb][0]=0.f; accs[s][nb][1]=0.f; accs[s][nb][2]=0.f; accs[s][nb][3]=0.f; }
#pragma unroll
        for (int nb = 0; nb < 4; ++nb) {
            bf16x8 b0 = *(const bf16x8*)&Kb[kc + (nb * 2 + 0) * 512 + lane * 8];
            bf16x8 b1 = *(const bf16x8*)&Kb[kc + (nb * 2 + 1) * 512 + lane * 8];
            accs[0][nb] = MFMA(qf[0][0], b0, accs[0][nb]);
            accs[0][nb] = MFMA(qf[0][1], b1, accs[0][nb]);
            accs[1][nb] = MFMA(qf[1][0], b0, accs[1][nb]);
            accs[1][nb] = MFMA(qf[1][1], b1, accs[1][nb]);
        }

        // ---- PV(t-1): V fragments shared across strips; P drained by prev barrier ----
        if (t > 0) {
            const int vc = ((t - 1) & 1) * 4096;
            bf16x8 pf00 = *(const bf16x8*)(pr0 + quad * 8);
            bf16x8 pf01 = *(const bf16x8*)(pr0 + 32 + quad * 8);
            bf16x8 pf10 = *(const bf16x8*)(pr1 + quad * 8);
            bf16x8 pf11 = *(const bf16x8*)(pr1 + 32 + quad * 8);
#pragma unroll
            for (int db = 0; db < 4; ++db) {
                bf16x8 v0 = *(const bf16x8*)&Vb[vc + (db * 2 + 0) * 512 + lane * 8];
                bf16x8 v1 = *(const bf16x8*)&Vb[vc + (db * 2 + 1) * 512 + lane * 8];
                acco[0][db] = MFMA(pf00, v0, acco[0][db]);
                acco[0][db] = MFMA(pf01, v1, acco[0][db]);
                acco[1][db] = MFMA(pf10, v0, acco[1][db]);
                acco[1][db] = MFMA(pf11, v1, acco[1][db]);
            }
        }

        // ---- p = mask ? exp2(s') : 0 ; row-sum partials; b64 P write ----
#pragma unroll
        for (int s = 0; s < 2; ++s) {
            short* pws = pw[s];
#pragma unroll
            for (int r = 0; r < 4; ++r) {
                const i32x4 mm = mcur[s][r];
                float e0 = fexp2(accs[s][0][r]); e0 = (mm[0] != 0) ? e0 : 0.f;
                float e1 = fexp2(accs[s][1][r]); e1 = (mm[1] != 0) ? e1 : 0.f;
                float e2 = fexp2(accs[s][2][r]); e2 = (mm[2] != 0) ? e2 : 0.f;
                float e3 = fexp2(accs[s][3][r]); e3 = (mm[3] != 0) ? e3 : 0.f;
                lacc[s][r] += (e0 + e1) + (e2 + e3);
                union { unsigned u[2]; s16x4 v; } pk;
                pk.u[0] = pk2(e0, e1);
                pk.u[1] = pk2(e2, e3);
                *(s16x4*)&pws[(quad * 4 + r) * PP + 4 * c] = pk.v;  // key pos 4c+nb
            }
        }
#pragma unroll
        for (int s = 0; s < 2; ++s)
#pragma unroll
            for (int r = 0; r < 4; ++r) mcur[s][r] = mnxt[s][r];
        __syncthreads();
    }

    // ---- drain: PV(NT-1) ----
    {
        const int vc = ((NT - 1) & 1) * 4096;
        bf16x8 pf00 = *(const bf16x8*)(pr0 + quad * 8);
        bf16x8 pf01 = *(const bf16x8*)(pr0 + 32 + quad * 8);
        bf16x8 pf10 = *(const bf16x8*)(pr1 + quad * 8);
        bf16x8 pf11 = *(const bf16x8*)(pr1 + 32 + quad * 8);
#pragma unroll
        for (int db = 0; db < 4; ++db) {
            bf16x8 v0 = *(const bf16x8*)&Vb[vc + (db * 2 + 0) * 512 + lane * 8];
            bf16x8 v1 = *(const bf16x8*)&Vb[vc + (db * 2 + 1) * 512 + lane * 8];
            acco[0][db] = MFMA(pf00, v0, acco[0][db]);
            acco[0][db] = MFMA(pf01, v1, acco[0][db]);
            acco[1][db] = MFMA(pf10, v0, acco[1][db]);
            acco[1][db] = MFMA(pf11, v1, acco[1][db]);
        }
    }

    // ---- epilogue ----
#pragma unroll
    for (int s = 0; s < 2; ++s) {
        float* orow = O + ((size_t)(bh * S_LEN + p * 128 + s * 64 + w * 16 + quad * 4)) * 64 + c;
#pragma unroll
        for (int r = 0; r < 4; ++r) {
            float l = lacc[s][r];
            l += __shfl_xor(l, 1);
            l += __shfl_xor(l, 2);
            l += __shfl_xor(l, 4);
            l += __shfl_xor(l, 8);
            float inv = 1.0f / l;
#pragma unroll
            for (int db = 0; db < 4; ++db)
                orow[(size_t)r * 64 + db * 16] = acco[s][db][r] * inv;
        }
    }
}

extern "C" void kernel_launch(void* const* d_in, const int* in_sizes, int n_in,
                              void* d_out, int out_size, void* d_ws, size_t ws_size,
                              hipStream_t stream) {
    const float* Q = (const float*)d_in[0];
    const float* K = (const float*)d_in[1];
    const float* V = (const float*)d_in[2];
    const int*   M = (const int*)d_in[3];
    float* O = (float*)d_out;

    short* Kw = (short*)d_ws;                       // 8 MB
    short* Vw = Kw + (size_t)32 * 32 * 4096;        // 8 MB

    hipLaunchKernelGGL(pack_kv, dim3(32, 32, 2), dim3(256), 0, stream, K, V, Kw, Vw);
    hipLaunchKernelGGL(fa_main, dim3(512), dim3(256), 0, stream, Q, Kw, Vw, M, O);
}